// Round 10
// baseline (494.521 us; speedup 1.0000x reference)
//
#include <hip/hip_runtime.h>
#include <hip/hip_bf16.h>

#define S 4096
#define DM 768
#define NH 12
#define DK 64
#define KSPLIT 4
#define KHALF (S / KSPLIT)
#define RPARTS 8
#define RCHUNK (S / RPARTS)

typedef __bf16 bf16x8 __attribute__((ext_vector_type(8)));
typedef __bf16 bf16x4 __attribute__((ext_vector_type(4)));
typedef float f32x4 __attribute__((ext_vector_type(4)));
using bf16 = __hip_bfloat16;

__device__ inline bf16x8 load_frag(const bf16* p) {
    return *reinterpret_cast<const bf16x8*>(p);
}

// Detect input dtype (f32 vs bf16) from bit patterns; flag=1 -> f32.
__global__ void k_detect(const unsigned int* __restrict__ q, int* __restrict__ flag) {
    const int lane = threadIdx.x;  // 64 threads
    int cnt = 0;
    for (int i = lane; i < 1024; i += 64) {
        const unsigned int w = q[i];
        const int e = (w >> 7) & 0xFF;
        if (e >= 192 || (e > 0 && e < 64)) cnt++;
    }
    for (int m = 1; m < 64; m <<= 1) cnt += __shfl_xor(cnt, m, 64);
    if (lane == 0) flag[0] = (cnt > 64) ? 1 : 0;
}

__device__ inline void cast_body(const void* src, bf16* dst, int n, int isf32) {
    const int stride = gridDim.x * 256 * 8;
    for (int i = (blockIdx.x * 256 + threadIdx.x) * 8; i < n; i += stride) {
        if (isf32) {
            const float* s = (const float*)src + i;
            float4 a = *(const float4*)(s);
            float4 b = *(const float4*)(s + 4);
            bf16x8 o;
            o[0] = (__bf16)a.x; o[1] = (__bf16)a.y; o[2] = (__bf16)a.z; o[3] = (__bf16)a.w;
            o[4] = (__bf16)b.x; o[5] = (__bf16)b.y; o[6] = (__bf16)b.z; o[7] = (__bf16)b.w;
            *reinterpret_cast<bf16x8*>(dst + i) = o;
        } else {
            *reinterpret_cast<bf16x8*>(dst + i) =
                *reinterpret_cast<const bf16x8*>((const __bf16*)src + i);
        }
    }
}

__global__ __launch_bounds__(256) void k_cast3(
    const void* s0, const void* s1, const void* s2,
    bf16* d0, bf16* d1, bf16* d2, int n, const int* __restrict__ flag) {
    const int t = blockIdx.y;
    const void* s = (t == 0) ? s0 : (t == 1) ? s1 : s2;
    bf16* d = (t == 0) ? d0 : (t == 1) ? d1 : d2;
    cast_body(s, d, n, flag[0]);
}

__global__ __launch_bounds__(256) void k_cast4(
    const void* s0, const void* s1, const void* s2, const void* s3,
    bf16* d0, bf16* d1, bf16* d2, bf16* d3, int n, const int* __restrict__ flag) {
    const int t = blockIdx.y;
    const void* s = (t == 0) ? s0 : (t == 1) ? s1 : (t == 2) ? s2 : s3;
    bf16* d = (t == 0) ? d0 : (t == 1) ? d1 : (t == 2) ? d2 : d3;
    cast_body(s, d, n, flag[0]);
}

// x @ W^T + b core. mode 0/1: head-split [H][S][DK]; mode 2: transposed [DM][S];
// mode 3: row-major [S][DM], dtype per flag.   (verified body)
__device__ inline void proj_body(
    const bf16* __restrict__ X, const bf16* __restrict__ W,
    const bf16* __restrict__ bias, void* __restrict__ dstv, int mode, int isf32)
{
    const int lane = threadIdx.x & 63;
    const int w    = threadIdx.x >> 6;
    const int lr   = lane & 15, lg = lane >> 4;
    const int rbase = blockIdx.x * 64 + w * 16;
    const int nbase = blockIdx.y * 64;

    f32x4 acc[4] = {};
    const bf16* xrow = X + (size_t)(rbase + lr) * DM + lg * 8;
    for (int kk = 0; kk < DM; kk += 32) {
        bf16x8 a = load_frag(xrow + kk);
#pragma unroll
        for (int nt = 0; nt < 4; ++nt) {
            bf16x8 b = load_frag(W + (size_t)(nbase + nt * 16 + lr) * DM + kk + lg * 8);
            acc[nt] = __builtin_amdgcn_mfma_f32_16x16x32_bf16(a, b, acc[nt], 0, 0, 0);
        }
    }
#pragma unroll
    for (int nt = 0; nt < 4; ++nt) {
        const int col = nbase + nt * 16 + lr;
        const float bv = __bfloat162float(bias[col]);
#pragma unroll
        for (int r = 0; r < 4; ++r) {
            const int row = rbase + lg * 4 + r;
            const float v = acc[nt][r] + bv;
            if (mode == 3) {
                const size_t off = (size_t)row * DM + col;
                if (isf32) ((float*)dstv)[off] = v;
                else       ((bf16*)dstv)[off] = __float2bfloat16(v);
            } else {
                size_t off;
                if (mode == 2) off = (size_t)col * S + row;
                else           off = (size_t)(col >> 6) * (S * DK) + (size_t)row * DK + (col & 63);
                ((bf16*)dstv)[off] = __float2bfloat16(v);
            }
        }
    }
}

// Fused Q/K/V projections: blockIdx.z selects tensor (0->qh, 1->kh, 2->vt).
__global__ __launch_bounds__(256) void k_proj_qkv(
    const bf16* __restrict__ Qc, const bf16* __restrict__ Kc, const bf16* __restrict__ Vc,
    const bf16* __restrict__ Wq, const bf16* __restrict__ Wk, const bf16* __restrict__ Wv,
    const bf16* __restrict__ bq, const bf16* __restrict__ bk, const bf16* __restrict__ bv,
    bf16* __restrict__ qh, bf16* __restrict__ kh, bf16* __restrict__ vt,
    const int* __restrict__ flag)
{
    const int z = blockIdx.z;
    const bf16* X = (z == 0) ? Qc : (z == 1) ? Kc : Vc;
    const bf16* W = (z == 0) ? Wq : (z == 1) ? Wk : Wv;
    const bf16* B = (z == 0) ? bq : (z == 1) ? bk : bv;
    bf16* D      = (z == 0) ? qh : (z == 1) ? kh : vt;
    proj_body(X, W, B, D, (z == 2) ? 2 : 0, flag[0]);
}

__global__ __launch_bounds__(256) void k_proj_out(
    const bf16* __restrict__ X, const bf16* __restrict__ W,
    const bf16* __restrict__ bias, void* __restrict__ dstv,
    const int* __restrict__ flag)
{
    proj_body(X, W, bias, dstv, 3, flag[0]);
}

// Partial row sums of exp(scores/8). Each wave: 64 q-rows (4x K-load reuse),
// k-range = RCHUNK per part. rs[part][h][q].  (verified R9)
__global__ __launch_bounds__(256) void k_rowsum(
    const bf16* __restrict__ qh, const bf16* __restrict__ kh,
    float* __restrict__ rs)
{
    const int lane = threadIdx.x & 63;
    const int w    = threadIdx.x >> 6;
    const int lr   = lane & 15;
    const int lg   = lane >> 4;
    const int h    = blockIdx.y;
    const int part = blockIdx.z;
    const int qw   = blockIdx.x * 256 + w * 64;

    const bf16* qb = qh + (size_t)h * (S * DK);
    const bf16* kb = kh + (size_t)h * (S * DK);
    bf16x8 aq[4][2];
#pragma unroll
    for (int qs = 0; qs < 4; ++qs) {
        aq[qs][0] = load_frag(qb + (size_t)(qw + qs * 16 + lr) * DK + lg * 8);
        aq[qs][1] = load_frag(qb + (size_t)(qw + qs * 16 + lr) * DK + 32 + lg * 8);
    }

    float s[4] = {0.f, 0.f, 0.f, 0.f};
    for (int kp = part * RCHUNK; kp < part * RCHUNK + RCHUNK; kp += 16) {
        bf16x8 b0 = load_frag(kb + (size_t)(kp + lr) * DK + lg * 8);
        bf16x8 b1 = load_frag(kb + (size_t)(kp + lr) * DK + 32 + lg * 8);
#pragma unroll
        for (int qs = 0; qs < 4; ++qs) {
            f32x4 d = {};
            d = __builtin_amdgcn_mfma_f32_16x16x32_bf16(b0, aq[qs][0], d, 0, 0, 0);
            d = __builtin_amdgcn_mfma_f32_16x16x32_bf16(b1, aq[qs][1], d, 0, 0, 0);
            s[qs] += __expf(d[0] * 0.125f) + __expf(d[1] * 0.125f) +
                     __expf(d[2] * 0.125f) + __expf(d[3] * 0.125f);
        }
    }
#pragma unroll
    for (int qs = 0; qs < 4; ++qs) {
        float v = s[qs];
        v += __shfl_xor(v, 16, 64);
        v += __shfl_xor(v, 32, 64);
        if (lg == 0)
            rs[((size_t)part * NH + h) * S + qw + qs * 16 + lr] = v;
    }
}

// R9-verified skeleton (qs=2, wave-private 32 q-rows, 2-tile LDS staging,
// V-prefetch, 512B nontemporal flush, no main-loop barrier), KSPLIT=4 for
// occupancy; ctx partials accumulated via f32 atomicAdd into zeroed ctxF.
__global__ __launch_bounds__(256) void k_attn(
    const bf16* __restrict__ qh, const bf16* __restrict__ kh,
    const bf16* __restrict__ vt, const float* __restrict__ rs,
    void* __restrict__ doutv, float* __restrict__ ctxF,
    const int* __restrict__ flag)
{
    __shared__ __align__(16) bf16 Plds[4][2][16][136];
    const int isf32 = flag[0];
    const int lane = threadIdx.x & 63;
    const int w    = threadIdx.x >> 6;
    const int lr   = lane & 15, lg = lane >> 4;
    const int h    = blockIdx.y;
    const int half = blockIdx.z;
    const int q0w  = blockIdx.x * 128 + w * 32;   // wave's 32-q base
    const int k0   = half * KHALF;

    const bf16* qb = qh + (size_t)h * (S * DK);
    const bf16* kb = kh + (size_t)h * (S * DK);
    const bf16* vb = vt + (size_t)h * (S * DK);

    bf16x8 aq[2][2];
    float  inv[2];
#pragma unroll
    for (int qs = 0; qs < 2; ++qs) {
        const int qr = q0w + qs * 16 + lr;
        aq[qs][0] = load_frag(qb + (size_t)qr * DK + lg * 8);
        aq[qs][1] = load_frag(qb + (size_t)qr * DK + 32 + lg * 8);
        float ssum = 0.f;
#pragma unroll
        for (int p = 0; p < RPARTS; ++p)
            ssum += rs[((size_t)p * NH + h) * S + qr];
        inv[qs] = 1.0f / ssum;
    }

    float* poutF = (float*)doutv + (size_t)S * DM + (size_t)h * S * S;
    bf16*  poutB = (bf16*)doutv  + (size_t)S * DM + (size_t)h * S * S;

    // flush mapping: half-wave -> row parity, lane&31 -> 4-col chunk
    const int fr2 = lane >> 5;          // 0..1
    const int fc2 = (lane & 31) * 4;    // 0..124

    f32x4 acc[2][4] = {};
    for (int tp = 0; tp < KHALF / 128; ++tp) {   // 8 iters of 2 tiles
#pragma unroll
        for (int tt = 0; tt < 2; ++tt) {
            const int kt = k0 + tp * 128 + tt * 64;
            const int cb = tt * 64;              // column base in Plds
            // ---- V prefetch for this tile (independent of P) ----
            bf16x8 vv[4][2];
#pragma unroll
            for (int dt = 0; dt < 4; ++dt) {
                vv[dt][0] = load_frag(vb + (size_t)(dt * 16 + lr) * S + kt + lg * 8);
                vv[dt][1] = load_frag(vb + (size_t)(dt * 16 + lr) * S + kt + 32 + lg * 8);
            }
            // ---- QK^T (swapped: D rows = k, cols = q), exp, stage bf16 ----
#pragma unroll
            for (int sub = 0; sub < 4; ++sub) {
                const int kp = kt + sub * 16;
                bf16x8 b0 = load_frag(kb + (size_t)(kp + lr) * DK + lg * 8);
                bf16x8 b1 = load_frag(kb + (size_t)(kp + lr) * DK + 32 + lg * 8);
#pragma unroll
                for (int qs = 0; qs < 2; ++qs) {
                    f32x4 d = {};
                    d = __builtin_amdgcn_mfma_f32_16x16x32_bf16(b0, aq[qs][0], d, 0, 0, 0);
                    d = __builtin_amdgcn_mfma_f32_16x16x32_bf16(b1, aq[qs][1], d, 0, 0, 0);
                    bf16x4 pv;
                    pv[0] = (__bf16)(__expf(d[0] * 0.125f) * inv[qs]);
                    pv[1] = (__bf16)(__expf(d[1] * 0.125f) * inv[qs]);
                    pv[2] = (__bf16)(__expf(d[2] * 0.125f) * inv[qs]);
                    pv[3] = (__bf16)(__expf(d[3] * 0.125f) * inv[qs]);
                    *reinterpret_cast<bf16x4*>(
                        &Plds[w][qs][lr][cb + sub * 16 + 4 * lg]) = pv;
                }
            }
            // ---- PV on this 64-k tile (prefetched V, shared across qs) ----
            bf16x8 ap[2][2];
#pragma unroll
            for (int qs = 0; qs < 2; ++qs) {
                ap[qs][0] = *reinterpret_cast<const bf16x8*>(&Plds[w][qs][lr][cb + lg * 8]);
                ap[qs][1] = *reinterpret_cast<const bf16x8*>(&Plds[w][qs][lr][cb + 32 + lg * 8]);
            }
#pragma unroll
            for (int dt = 0; dt < 4; ++dt) {
#pragma unroll
                for (int qs = 0; qs < 2; ++qs) {
                    acc[qs][dt] = __builtin_amdgcn_mfma_f32_16x16x32_bf16(ap[qs][0], vv[dt][0], acc[qs][dt], 0, 0, 0);
                    acc[qs][dt] = __builtin_amdgcn_mfma_f32_16x16x32_bf16(ap[qs][1], vv[dt][1], acc[qs][dt], 0, 0, 0);
                }
            }
        }
        // ---- flush 2 tiles: 32 rows x 128 cols ----
        const int ktbase = k0 + tp * 128;
        if (isf32) {
#pragma unroll
            for (int j = 0; j < 16; ++j) {
                const int row = 2 * j + fr2;           // 0..31
                const int qs = row >> 4, rr = row & 15;
                bf16x4 x = *reinterpret_cast<const bf16x4*>(&Plds[w][qs][rr][fc2]);
                f32x4 o;
                o[0] = (float)x[0]; o[1] = (float)x[1];
                o[2] = (float)x[2]; o[3] = (float)x[3];
                __builtin_nontemporal_store(
                    o, reinterpret_cast<f32x4*>(
                           poutF + (size_t)(q0w + row) * S + ktbase + fc2));
            }
        } else {
#pragma unroll
            for (int j = 0; j < 16; ++j) {
                const int row = 2 * j + fr2;
                const int qs = row >> 4, rr = row & 15;
                bf16x4 x = *reinterpret_cast<const bf16x4*>(&Plds[w][qs][rr][fc2]);
                *reinterpret_cast<bf16x4*>(
                    poutB + (size_t)(q0w + row) * S + ktbase + fc2) = x;
            }
        }
    }
    // epilogue: accumulate partial ctx in f32 (device-scope atomics)
#pragma unroll
    for (int qs = 0; qs < 2; ++qs)
#pragma unroll
        for (int dt = 0; dt < 4; ++dt)
#pragma unroll
            for (int r = 0; r < 4; ++r)
                atomicAdd(&ctxF[(size_t)(q0w + qs * 16 + 4 * lg + r) * DM +
                                h * DK + dt * 16 + lr], acc[qs][dt][r]);
}

// zero ctxF
__global__ __launch_bounds__(256) void k_zero(float* __restrict__ p) {
    const int i = (blockIdx.x * 256 + threadIdx.x) * 4;
    f32x4 z = {};
    *reinterpret_cast<f32x4*>(p + i) = z;
}

// ctx (bf16) = ctxF (f32)
__global__ __launch_bounds__(256) void k_reduce(const float* __restrict__ ctxF,
                                               bf16* __restrict__ ctx) {
    const int i = (blockIdx.x * 256 + threadIdx.x) * 8;
    f32x4 a = *reinterpret_cast<const f32x4*>(ctxF + i);
    f32x4 b = *reinterpret_cast<const f32x4*>(ctxF + i + 4);
    bf16x8 o;
#pragma unroll
    for (int j = 0; j < 4; ++j) o[j] = (__bf16)a[j];
#pragma unroll
    for (int j = 0; j < 4; ++j) o[4 + j] = (__bf16)b[j];
    *reinterpret_cast<bf16x8*>(ctx + i) = o;
}

extern "C" void kernel_launch(void* const* d_in, const int* in_sizes, int n_in,
                              void* d_out, int out_size, void* d_ws, size_t ws_size,
                              hipStream_t stream) {
    char* wsb = (char*)d_ws;
    int*   flag = (int*)wsb;                                    // 16 B
    float* rs   = (float*)(wsb + 16);                           // RPARTS*NH*S f32
    bf16*  conv = (bf16*)(wsb + 16 + (size_t)RPARTS * NH * S * 4);

    const size_t nQ = (size_t)S * DM, nW = (size_t)DM * DM, nB = DM;
    bf16* Qc  = conv;
    bf16* Kc  = Qc + nQ;
    bf16* Vc  = Kc + nQ;
    bf16* Wqc = Vc + nQ;
    bf16* Wkc = Wqc + nW;
    bf16* Wvc = Wkc + nW;
    bf16* Woc = Wvc + nW;
    bf16* bqc = Woc + nW;
    bf16* bkc = bqc + nB;
    bf16* bvc = bkc + nB;
    bf16* boc = bvc + nB;
    bf16* qh  = boc + nB;
    bf16* kh  = qh + nQ;
    bf16* vt  = kh + nQ;
    // aliases (Qc/Kc/Vc dead after projections):
    float* ctxF = (float*)Qc;   // nQ f32 == 2*nQ bf16 (Qc+Kc region)
    bf16*  ctx  = Vc;           // nQ bf16

    const size_t need = (size_t)((char*)(vt + nQ) - wsb);
    if (ws_size < need) return;

    dim3 blk(256);
    k_detect<<<1, 64, 0, stream>>>((const unsigned int*)d_in[0], flag);

    k_cast3<<<dim3((int)(nQ / 2048), 3), blk, 0, stream>>>(
        d_in[0], d_in[1], d_in[2], Qc, Kc, Vc, (int)nQ, flag);
    k_cast4<<<dim3((int)(nW / 2048), 4), blk, 0, stream>>>(
        d_in[3], d_in[5], d_in[7], d_in[9], Wqc, Wkc, Wvc, Woc, (int)nW, flag);
    k_cast4<<<dim3(1, 4), blk, 0, stream>>>(
        d_in[4], d_in[6], d_in[8], d_in[10], bqc, bkc, bvc, boc, (int)nB, flag);

    k_proj_qkv<<<dim3(S / 64, DM / 64, 3), blk, 0, stream>>>(
        Qc, Kc, Vc, Wqc, Wkc, Wvc, bqc, bkc, bvc, qh, kh, vt, flag);
    k_zero<<<dim3((int)(nQ / 1024)), blk, 0, stream>>>(ctxF);
    k_rowsum<<<dim3(S / 256, NH, RPARTS), blk, 0, stream>>>(qh, kh, rs);
    k_attn<<<dim3(S / 128, NH, KSPLIT), blk, 0, stream>>>(qh, kh, vt, rs, d_out, ctxF, flag);
    k_reduce<<<dim3((int)(nQ / 2048)), blk, 0, stream>>>(ctxF, ctx);
    k_proj_out<<<dim3(S / 64, DM / 64), blk, 0, stream>>>(ctx, Woc, boc, d_out, flag);
}

// Round 11
// 470.444 us; speedup vs baseline: 1.0512x; 1.0512x over previous
//
#include <hip/hip_runtime.h>
#include <hip/hip_bf16.h>

#define S 4096
#define DM 768
#define NH 12
#define DK 64
#define KSPLIT 2
#define KHALF (S / KSPLIT)
#define RPARTS 8
#define RCHUNK (S / RPARTS)

typedef __bf16 bf16x8 __attribute__((ext_vector_type(8)));
typedef __bf16 bf16x4 __attribute__((ext_vector_type(4)));
typedef float f32x4 __attribute__((ext_vector_type(4)));
using bf16 = __hip_bfloat16;

__device__ inline bf16x8 load_frag(const bf16* p) {
    return *reinterpret_cast<const bf16x8*>(p);
}

// Detect input dtype (f32 vs bf16) from bit patterns; flag=1 -> f32.
__global__ void k_detect(const unsigned int* __restrict__ q, int* __restrict__ flag) {
    const int lane = threadIdx.x;  // 64 threads
    int cnt = 0;
    for (int i = lane; i < 1024; i += 64) {
        const unsigned int w = q[i];
        const int e = (w >> 7) & 0xFF;
        if (e >= 192 || (e > 0 && e < 64)) cnt++;
    }
    for (int m = 1; m < 64; m <<= 1) cnt += __shfl_xor(cnt, m, 64);
    if (lane == 0) flag[0] = (cnt > 64) ? 1 : 0;
}

__device__ inline void cast_body(const void* src, bf16* dst, int n, int isf32) {
    const int stride = gridDim.x * 256 * 8;
    for (int i = (blockIdx.x * 256 + threadIdx.x) * 8; i < n; i += stride) {
        if (isf32) {
            const float* s = (const float*)src + i;
            float4 a = *(const float4*)(s);
            float4 b = *(const float4*)(s + 4);
            bf16x8 o;
            o[0] = (__bf16)a.x; o[1] = (__bf16)a.y; o[2] = (__bf16)a.z; o[3] = (__bf16)a.w;
            o[4] = (__bf16)b.x; o[5] = (__bf16)b.y; o[6] = (__bf16)b.z; o[7] = (__bf16)b.w;
            *reinterpret_cast<bf16x8*>(dst + i) = o;
        } else {
            *reinterpret_cast<bf16x8*>(dst + i) =
                *reinterpret_cast<const bf16x8*>((const __bf16*)src + i);
        }
    }
}

__global__ __launch_bounds__(256) void k_cast3(
    const void* s0, const void* s1, const void* s2,
    bf16* d0, bf16* d1, bf16* d2, int n, const int* __restrict__ flag) {
    const int t = blockIdx.y;
    const void* s = (t == 0) ? s0 : (t == 1) ? s1 : s2;
    bf16* d = (t == 0) ? d0 : (t == 1) ? d1 : d2;
    cast_body(s, d, n, flag[0]);
}

__global__ __launch_bounds__(256) void k_cast4(
    const void* s0, const void* s1, const void* s2, const void* s3,
    bf16* d0, bf16* d1, bf16* d2, bf16* d3, int n, const int* __restrict__ flag) {
    const int t = blockIdx.y;
    const void* s = (t == 0) ? s0 : (t == 1) ? s1 : (t == 2) ? s2 : s3;
    bf16* d = (t == 0) ? d0 : (t == 1) ? d1 : (t == 2) ? d2 : d3;
    cast_body(s, d, n, flag[0]);
}

// x @ W^T + b core. mode 0/1: head-split [H][S][DK]; mode 2: transposed [DM][S].
__device__ inline void proj_body(
    const bf16* __restrict__ X, const bf16* __restrict__ W,
    const bf16* __restrict__ bias, void* __restrict__ dstv, int mode, int isf32)
{
    const int lane = threadIdx.x & 63;
    const int w    = threadIdx.x >> 6;
    const int lr   = lane & 15, lg = lane >> 4;
    const int rbase = blockIdx.x * 64 + w * 16;
    const int nbase = blockIdx.y * 64;

    f32x4 acc[4] = {};
    const bf16* xrow = X + (size_t)(rbase + lr) * DM + lg * 8;
    for (int kk = 0; kk < DM; kk += 32) {
        bf16x8 a = load_frag(xrow + kk);
#pragma unroll
        for (int nt = 0; nt < 4; ++nt) {
            bf16x8 b = load_frag(W + (size_t)(nbase + nt * 16 + lr) * DM + kk + lg * 8);
            acc[nt] = __builtin_amdgcn_mfma_f32_16x16x32_bf16(a, b, acc[nt], 0, 0, 0);
        }
    }
#pragma unroll
    for (int nt = 0; nt < 4; ++nt) {
        const int col = nbase + nt * 16 + lr;
        const float bv = __bfloat162float(bias[col]);
#pragma unroll
        for (int r = 0; r < 4; ++r) {
            const int row = rbase + lg * 4 + r;
            const float v = acc[nt][r] + bv;
            size_t off;
            if (mode == 2) off = (size_t)col * S + row;
            else           off = (size_t)(col >> 6) * (S * DK) + (size_t)row * DK + (col & 63);
            ((bf16*)dstv)[off] = __float2bfloat16(v);
        }
    }
}

// Fused Q/K/V projections: blockIdx.z selects tensor (0->qh, 1->kh, 2->vt).
__global__ __launch_bounds__(256) void k_proj_qkv(
    const bf16* __restrict__ Qc, const bf16* __restrict__ Kc, const bf16* __restrict__ Vc,
    const bf16* __restrict__ Wq, const bf16* __restrict__ Wk, const bf16* __restrict__ Wv,
    const bf16* __restrict__ bq, const bf16* __restrict__ bk, const bf16* __restrict__ bv,
    bf16* __restrict__ qh, bf16* __restrict__ kh, bf16* __restrict__ vt,
    const int* __restrict__ flag)
{
    const int z = blockIdx.z;
    const bf16* X = (z == 0) ? Qc : (z == 1) ? Kc : Vc;
    const bf16* W = (z == 0) ? Wq : (z == 1) ? Wk : Wv;
    const bf16* B = (z == 0) ? bq : (z == 1) ? bk : bv;
    bf16* D      = (z == 0) ? qh : (z == 1) ? kh : vt;
    proj_body(X, W, B, D, (z == 2) ? 2 : 0, flag[0]);
}

// Output projection with fused partial-ctx reduction: X = ctxp0 + ctxp1
// (same bf16 rounding point as the old k_reduce -> identical numerics).
__global__ __launch_bounds__(256) void k_proj_out(
    const bf16* __restrict__ ctxp, const bf16* __restrict__ W,
    const bf16* __restrict__ bias, void* __restrict__ dstv,
    const int* __restrict__ flag)
{
    const int isf32 = flag[0];
    const int lane = threadIdx.x & 63;
    const int w    = threadIdx.x >> 6;
    const int lr   = lane & 15, lg = lane >> 4;
    const int rbase = blockIdx.x * 64 + w * 16;
    const int nbase = blockIdx.y * 64;

    f32x4 acc[4] = {};
    const bf16* x0 = ctxp + (size_t)(rbase + lr) * DM + lg * 8;
    const bf16* x1 = x0 + (size_t)S * DM;
    for (int kk = 0; kk < DM; kk += 32) {
        bf16x8 a0 = load_frag(x0 + kk);
        bf16x8 a1 = load_frag(x1 + kk);
        bf16x8 a;
#pragma unroll
        for (int j = 0; j < 8; ++j)
            a[j] = (__bf16)((float)a0[j] + (float)a1[j]);
#pragma unroll
        for (int nt = 0; nt < 4; ++nt) {
            bf16x8 b = load_frag(W + (size_t)(nbase + nt * 16 + lr) * DM + kk + lg * 8);
            acc[nt] = __builtin_amdgcn_mfma_f32_16x16x32_bf16(a, b, acc[nt], 0, 0, 0);
        }
    }
#pragma unroll
    for (int nt = 0; nt < 4; ++nt) {
        const int col = nbase + nt * 16 + lr;
        const float bv = __bfloat162float(bias[col]);
#pragma unroll
        for (int r = 0; r < 4; ++r) {
            const int row = rbase + lg * 4 + r;
            const float v = acc[nt][r] + bv;
            const size_t off = (size_t)row * DM + col;
            if (isf32) ((float*)dstv)[off] = v;
            else       ((bf16*)dstv)[off] = __float2bfloat16(v);
        }
    }
}

// Partial row sums of exp(scores/8). Each wave: 64 q-rows (4x K-load reuse),
// k-range = RCHUNK per part. rs[part][h][q].  (verified R9)
__global__ __launch_bounds__(256) void k_rowsum(
    const bf16* __restrict__ qh, const bf16* __restrict__ kh,
    float* __restrict__ rs)
{
    const int lane = threadIdx.x & 63;
    const int w    = threadIdx.x >> 6;
    const int lr   = lane & 15;
    const int lg   = lane >> 4;
    const int h    = blockIdx.y;
    const int part = blockIdx.z;
    const int qw   = blockIdx.x * 256 + w * 64;

    const bf16* qb = qh + (size_t)h * (S * DK);
    const bf16* kb = kh + (size_t)h * (S * DK);
    bf16x8 aq[4][2];
#pragma unroll
    for (int qs = 0; qs < 4; ++qs) {
        aq[qs][0] = load_frag(qb + (size_t)(qw + qs * 16 + lr) * DK + lg * 8);
        aq[qs][1] = load_frag(qb + (size_t)(qw + qs * 16 + lr) * DK + 32 + lg * 8);
    }

    float s[4] = {0.f, 0.f, 0.f, 0.f};
    for (int kp = part * RCHUNK; kp < part * RCHUNK + RCHUNK; kp += 16) {
        bf16x8 b0 = load_frag(kb + (size_t)(kp + lr) * DK + lg * 8);
        bf16x8 b1 = load_frag(kb + (size_t)(kp + lr) * DK + 32 + lg * 8);
#pragma unroll
        for (int qs = 0; qs < 4; ++qs) {
            f32x4 d = {};
            d = __builtin_amdgcn_mfma_f32_16x16x32_bf16(b0, aq[qs][0], d, 0, 0, 0);
            d = __builtin_amdgcn_mfma_f32_16x16x32_bf16(b1, aq[qs][1], d, 0, 0, 0);
            s[qs] += __expf(d[0] * 0.125f) + __expf(d[1] * 0.125f) +
                     __expf(d[2] * 0.125f) + __expf(d[3] * 0.125f);
        }
    }
#pragma unroll
    for (int qs = 0; qs < 4; ++qs) {
        float v = s[qs];
        v += __shfl_xor(v, 16, 64);
        v += __shfl_xor(v, 32, 64);
        if (lg == 0)
            rs[((size_t)part * NH + h) * S + qw + qs * 16 + lr] = v;
    }
}

// R9-verified k_attn: qs=2 (wave-private 32 q-rows), 2-tile LDS staging,
// V-prefetch, 512B nontemporal flush, no main-loop barrier, KSPLIT=2,
// bf16 ctxp partial epilogue.
__global__ __launch_bounds__(256) void k_attn(
    const bf16* __restrict__ qh, const bf16* __restrict__ kh,
    const bf16* __restrict__ vt, const float* __restrict__ rs,
    void* __restrict__ doutv, bf16* __restrict__ ctxp,
    const int* __restrict__ flag)
{
    __shared__ __align__(16) bf16 Plds[4][2][16][136];
    const int isf32 = flag[0];
    const int lane = threadIdx.x & 63;
    const int w    = threadIdx.x >> 6;
    const int lr   = lane & 15, lg = lane >> 4;
    const int h    = blockIdx.y;
    const int half = blockIdx.z;
    const int q0w  = blockIdx.x * 128 + w * 32;   // wave's 32-q base
    const int k0   = half * KHALF;

    const bf16* qb = qh + (size_t)h * (S * DK);
    const bf16* kb = kh + (size_t)h * (S * DK);
    const bf16* vb = vt + (size_t)h * (S * DK);

    bf16x8 aq[2][2];
    float  inv[2];
#pragma unroll
    for (int qs = 0; qs < 2; ++qs) {
        const int qr = q0w + qs * 16 + lr;
        aq[qs][0] = load_frag(qb + (size_t)qr * DK + lg * 8);
        aq[qs][1] = load_frag(qb + (size_t)qr * DK + 32 + lg * 8);
        float ssum = 0.f;
#pragma unroll
        for (int p = 0; p < RPARTS; ++p)
            ssum += rs[((size_t)p * NH + h) * S + qr];
        inv[qs] = 1.0f / ssum;
    }

    float* poutF = (float*)doutv + (size_t)S * DM + (size_t)h * S * S;
    bf16*  poutB = (bf16*)doutv  + (size_t)S * DM + (size_t)h * S * S;

    // flush mapping: half-wave -> row parity, lane&31 -> 4-col chunk
    const int fr2 = lane >> 5;          // 0..1
    const int fc2 = (lane & 31) * 4;    // 0..124

    f32x4 acc[2][4] = {};
    for (int tp = 0; tp < KHALF / 128; ++tp) {   // 16 iters of 2 tiles
#pragma unroll
        for (int tt = 0; tt < 2; ++tt) {
            const int kt = k0 + tp * 128 + tt * 64;
            const int cb = tt * 64;              // column base in Plds
            // ---- V prefetch for this tile (independent of P) ----
            bf16x8 vv[4][2];
#pragma unroll
            for (int dt = 0; dt < 4; ++dt) {
                vv[dt][0] = load_frag(vb + (size_t)(dt * 16 + lr) * S + kt + lg * 8);
                vv[dt][1] = load_frag(vb + (size_t)(dt * 16 + lr) * S + kt + 32 + lg * 8);
            }
            // ---- QK^T (swapped: D rows = k, cols = q), exp, stage bf16 ----
#pragma unroll
            for (int sub = 0; sub < 4; ++sub) {
                const int kp = kt + sub * 16;
                bf16x8 b0 = load_frag(kb + (size_t)(kp + lr) * DK + lg * 8);
                bf16x8 b1 = load_frag(kb + (size_t)(kp + lr) * DK + 32 + lg * 8);
#pragma unroll
                for (int qs = 0; qs < 2; ++qs) {
                    f32x4 d = {};
                    d = __builtin_amdgcn_mfma_f32_16x16x32_bf16(b0, aq[qs][0], d, 0, 0, 0);
                    d = __builtin_amdgcn_mfma_f32_16x16x32_bf16(b1, aq[qs][1], d, 0, 0, 0);
                    bf16x4 pv;
                    pv[0] = (__bf16)(__expf(d[0] * 0.125f) * inv[qs]);
                    pv[1] = (__bf16)(__expf(d[1] * 0.125f) * inv[qs]);
                    pv[2] = (__bf16)(__expf(d[2] * 0.125f) * inv[qs]);
                    pv[3] = (__bf16)(__expf(d[3] * 0.125f) * inv[qs]);
                    *reinterpret_cast<bf16x4*>(
                        &Plds[w][qs][lr][cb + sub * 16 + 4 * lg]) = pv;
                }
            }
            // ---- PV on this 64-k tile (prefetched V, shared across qs) ----
            bf16x8 ap[2][2];
#pragma unroll
            for (int qs = 0; qs < 2; ++qs) {
                ap[qs][0] = *reinterpret_cast<const bf16x8*>(&Plds[w][qs][lr][cb + lg * 8]);
                ap[qs][1] = *reinterpret_cast<const bf16x8*>(&Plds[w][qs][lr][cb + 32 + lg * 8]);
            }
#pragma unroll
            for (int dt = 0; dt < 4; ++dt) {
#pragma unroll
                for (int qs = 0; qs < 2; ++qs) {
                    acc[qs][dt] = __builtin_amdgcn_mfma_f32_16x16x32_bf16(ap[qs][0], vv[dt][0], acc[qs][dt], 0, 0, 0);
                    acc[qs][dt] = __builtin_amdgcn_mfma_f32_16x16x32_bf16(ap[qs][1], vv[dt][1], acc[qs][dt], 0, 0, 0);
                }
            }
        }
        // ---- flush 2 tiles: 32 rows x 128 cols ----
        const int ktbase = k0 + tp * 128;
        if (isf32) {
#pragma unroll
            for (int j = 0; j < 16; ++j) {
                const int row = 2 * j + fr2;           // 0..31
                const int qs = row >> 4, rr = row & 15;
                bf16x4 x = *reinterpret_cast<const bf16x4*>(&Plds[w][qs][rr][fc2]);
                f32x4 o;
                o[0] = (float)x[0]; o[1] = (float)x[1];
                o[2] = (float)x[2]; o[3] = (float)x[3];
                __builtin_nontemporal_store(
                    o, reinterpret_cast<f32x4*>(
                           poutF + (size_t)(q0w + row) * S + ktbase + fc2));
            }
        } else {
#pragma unroll
            for (int j = 0; j < 16; ++j) {
                const int row = 2 * j + fr2;
                const int qs = row >> 4, rr = row & 15;
                bf16x4 x = *reinterpret_cast<const bf16x4*>(&Plds[w][qs][rr][fc2]);
                *reinterpret_cast<bf16x4*>(
                    poutB + (size_t)(q0w + row) * S + ktbase + fc2) = x;
            }
        }
    }
    bf16* cp = ctxp + (size_t)half * S * DM;
#pragma unroll
    for (int qs = 0; qs < 2; ++qs)
#pragma unroll
        for (int dt = 0; dt < 4; ++dt)
#pragma unroll
            for (int r = 0; r < 4; ++r)
                cp[(size_t)(q0w + qs * 16 + 4 * lg + r) * DM + h * DK + dt * 16 + lr] =
                    __float2bfloat16(acc[qs][dt][r]);
}

extern "C" void kernel_launch(void* const* d_in, const int* in_sizes, int n_in,
                              void* d_out, int out_size, void* d_ws, size_t ws_size,
                              hipStream_t stream) {
    char* wsb = (char*)d_ws;
    int*   flag = (int*)wsb;                                    // 16 B
    float* rs   = (float*)(wsb + 16);                           // RPARTS*NH*S f32
    bf16*  conv = (bf16*)(wsb + 16 + (size_t)RPARTS * NH * S * 4);

    const size_t nQ = (size_t)S * DM, nW = (size_t)DM * DM, nB = DM;
    bf16* Qc  = conv;
    bf16* Kc  = Qc + nQ;
    bf16* Vc  = Kc + nQ;
    bf16* Wqc = Vc + nQ;
    bf16* Wkc = Wqc + nW;
    bf16* Wvc = Wkc + nW;
    bf16* Woc = Wvc + nW;
    bf16* bqc = Woc + nW;
    bf16* bkc = bqc + nB;
    bf16* bvc = bkc + nB;
    bf16* boc = bvc + nB;
    bf16* qh  = boc + nB;
    bf16* kh  = qh + nQ;
    bf16* vt  = kh + nQ;
    // alias (Qc/Kc dead after projections): ctxp = 2*nQ bf16 partial ctx
    bf16* ctxp = Qc;

    const size_t need = (size_t)((char*)(vt + nQ) - wsb);
    if (ws_size < need) return;

    dim3 blk(256);
    k_detect<<<1, 64, 0, stream>>>((const unsigned int*)d_in[0], flag);

    k_cast3<<<dim3((int)(nQ / 2048), 3), blk, 0, stream>>>(
        d_in[0], d_in[1], d_in[2], Qc, Kc, Vc, (int)nQ, flag);
    k_cast4<<<dim3((int)(nW / 2048), 4), blk, 0, stream>>>(
        d_in[3], d_in[5], d_in[7], d_in[9], Wqc, Wkc, Wvc, Woc, (int)nW, flag);
    k_cast4<<<dim3(1, 4), blk, 0, stream>>>(
        d_in[4], d_in[6], d_in[8], d_in[10], bqc, bkc, bvc, boc, (int)nB, flag);

    k_proj_qkv<<<dim3(S / 64, DM / 64, 3), blk, 0, stream>>>(
        Qc, Kc, Vc, Wqc, Wkc, Wvc, bqc, bkc, bvc, qh, kh, vt, flag);
    k_rowsum<<<dim3(S / 256, NH, RPARTS), blk, 0, stream>>>(qh, kh, rs);
    k_attn<<<dim3(S / 128, NH, KSPLIT), blk, 0, stream>>>(qh, kh, vt, rs, d_out, ctxp, flag);
    k_proj_out<<<dim3(S / 64, DM / 64), blk, 0, stream>>>(ctxp, Woc, boc, d_out, flag);
}

// Round 12
// 468.475 us; speedup vs baseline: 1.0556x; 1.0042x over previous
//
#include <hip/hip_runtime.h>
#include <hip/hip_bf16.h>

#define S 4096
#define DM 768
#define NH 12
#define DK 64
#define KSPLIT 2
#define KHALF (S / KSPLIT)
#define RPARTS 8
#define RCHUNK (S / RPARTS)

typedef __bf16 bf16x8 __attribute__((ext_vector_type(8)));
typedef __bf16 bf16x4 __attribute__((ext_vector_type(4)));
typedef float f32x4 __attribute__((ext_vector_type(4)));
using bf16 = __hip_bfloat16;

__device__ inline bf16x8 load_frag(const bf16* p) {
    return *reinterpret_cast<const bf16x8*>(p);
}

// Detect input dtype (f32 vs bf16) from bit patterns; flag=1 -> f32.
__global__ void k_detect(const unsigned int* __restrict__ q, int* __restrict__ flag) {
    const int lane = threadIdx.x;  // 64 threads
    int cnt = 0;
    for (int i = lane; i < 1024; i += 64) {
        const unsigned int w = q[i];
        const int e = (w >> 7) & 0xFF;
        if (e >= 192 || (e > 0 && e < 64)) cnt++;
    }
    for (int m = 1; m < 64; m <<= 1) cnt += __shfl_xor(cnt, m, 64);
    if (lane == 0) flag[0] = (cnt > 64) ? 1 : 0;
}

__device__ inline void cast_body(const void* src, bf16* dst, int n, int isf32) {
    const int stride = gridDim.x * 256 * 8;
    for (int i = (blockIdx.x * 256 + threadIdx.x) * 8; i < n; i += stride) {
        if (isf32) {
            const float* s = (const float*)src + i;
            float4 a = *(const float4*)(s);
            float4 b = *(const float4*)(s + 4);
            bf16x8 o;
            o[0] = (__bf16)a.x; o[1] = (__bf16)a.y; o[2] = (__bf16)a.z; o[3] = (__bf16)a.w;
            o[4] = (__bf16)b.x; o[5] = (__bf16)b.y; o[6] = (__bf16)b.z; o[7] = (__bf16)b.w;
            *reinterpret_cast<bf16x8*>(dst + i) = o;
        } else {
            *reinterpret_cast<bf16x8*>(dst + i) =
                *reinterpret_cast<const bf16x8*>((const __bf16*)src + i);
        }
    }
}

__global__ __launch_bounds__(256) void k_cast3(
    const void* s0, const void* s1, const void* s2,
    bf16* d0, bf16* d1, bf16* d2, int n, const int* __restrict__ flag) {
    const int t = blockIdx.y;
    const void* s = (t == 0) ? s0 : (t == 1) ? s1 : s2;
    bf16* d = (t == 0) ? d0 : (t == 1) ? d1 : d2;
    cast_body(s, d, n, flag[0]);
}

__global__ __launch_bounds__(256) void k_cast4(
    const void* s0, const void* s1, const void* s2, const void* s3,
    bf16* d0, bf16* d1, bf16* d2, bf16* d3, int n, const int* __restrict__ flag) {
    const int t = blockIdx.y;
    const void* s = (t == 0) ? s0 : (t == 1) ? s1 : (t == 2) ? s2 : s3;
    bf16* d = (t == 0) ? d0 : (t == 1) ? d1 : (t == 2) ? d2 : d3;
    cast_body(s, d, n, flag[0]);
}

// x @ W^T + b core. mode 0/1: head-split [H][S][DK]; mode 2: transposed [DM][S].
__device__ inline void proj_body(
    const bf16* __restrict__ X, const bf16* __restrict__ W,
    const bf16* __restrict__ bias, void* __restrict__ dstv, int mode, int isf32)
{
    const int lane = threadIdx.x & 63;
    const int w    = threadIdx.x >> 6;
    const int lr   = lane & 15, lg = lane >> 4;
    const int rbase = blockIdx.x * 64 + w * 16;
    const int nbase = blockIdx.y * 64;

    f32x4 acc[4] = {};
    const bf16* xrow = X + (size_t)(rbase + lr) * DM + lg * 8;
    for (int kk = 0; kk < DM; kk += 32) {
        bf16x8 a = load_frag(xrow + kk);
#pragma unroll
        for (int nt = 0; nt < 4; ++nt) {
            bf16x8 b = load_frag(W + (size_t)(nbase + nt * 16 + lr) * DM + kk + lg * 8);
            acc[nt] = __builtin_amdgcn_mfma_f32_16x16x32_bf16(a, b, acc[nt], 0, 0, 0);
        }
    }
#pragma unroll
    for (int nt = 0; nt < 4; ++nt) {
        const int col = nbase + nt * 16 + lr;
        const float bv = __bfloat162float(bias[col]);
#pragma unroll
        for (int r = 0; r < 4; ++r) {
            const int row = rbase + lg * 4 + r;
            const float v = acc[nt][r] + bv;
            size_t off;
            if (mode == 2) off = (size_t)col * S + row;
            else           off = (size_t)(col >> 6) * (S * DK) + (size_t)row * DK + (col & 63);
            ((bf16*)dstv)[off] = __float2bfloat16(v);
        }
    }
}

// Fused Q/K/V projections: blockIdx.z selects tensor (0->qh, 1->kh, 2->vt).
__global__ __launch_bounds__(256) void k_proj_qkv(
    const bf16* __restrict__ Qc, const bf16* __restrict__ Kc, const bf16* __restrict__ Vc,
    const bf16* __restrict__ Wq, const bf16* __restrict__ Wk, const bf16* __restrict__ Wv,
    const bf16* __restrict__ bq, const bf16* __restrict__ bk, const bf16* __restrict__ bv,
    bf16* __restrict__ qh, bf16* __restrict__ kh, bf16* __restrict__ vt,
    const int* __restrict__ flag)
{
    const int z = blockIdx.z;
    const bf16* X = (z == 0) ? Qc : (z == 1) ? Kc : Vc;
    const bf16* W = (z == 0) ? Wq : (z == 1) ? Wk : Wv;
    const bf16* B = (z == 0) ? bq : (z == 1) ? bk : bv;
    bf16* D      = (z == 0) ? qh : (z == 1) ? kh : vt;
    proj_body(X, W, B, D, (z == 2) ? 2 : 0, flag[0]);
}

// Output projection with fused partial-ctx reduction: X = ctxp0 + ctxp1.
__global__ __launch_bounds__(256) void k_proj_out(
    const bf16* __restrict__ ctxp, const bf16* __restrict__ W,
    const bf16* __restrict__ bias, void* __restrict__ dstv,
    const int* __restrict__ flag)
{
    const int isf32 = flag[0];
    const int lane = threadIdx.x & 63;
    const int w    = threadIdx.x >> 6;
    const int lr   = lane & 15, lg = lane >> 4;
    const int rbase = blockIdx.x * 64 + w * 16;
    const int nbase = blockIdx.y * 64;

    f32x4 acc[4] = {};
    const bf16* x0 = ctxp + (size_t)(rbase + lr) * DM + lg * 8;
    const bf16* x1 = x0 + (size_t)S * DM;
    for (int kk = 0; kk < DM; kk += 32) {
        bf16x8 a0 = load_frag(x0 + kk);
        bf16x8 a1 = load_frag(x1 + kk);
        bf16x8 a;
#pragma unroll
        for (int j = 0; j < 8; ++j)
            a[j] = (__bf16)((float)a0[j] + (float)a1[j]);
#pragma unroll
        for (int nt = 0; nt < 4; ++nt) {
            bf16x8 b = load_frag(W + (size_t)(nbase + nt * 16 + lr) * DM + kk + lg * 8);
            acc[nt] = __builtin_amdgcn_mfma_f32_16x16x32_bf16(a, b, acc[nt], 0, 0, 0);
        }
    }
#pragma unroll
    for (int nt = 0; nt < 4; ++nt) {
        const int col = nbase + nt * 16 + lr;
        const float bv = __bfloat162float(bias[col]);
#pragma unroll
        for (int r = 0; r < 4; ++r) {
            const int row = rbase + lg * 4 + r;
            const float v = acc[nt][r] + bv;
            const size_t off = (size_t)row * DM + col;
            if (isf32) ((float*)dstv)[off] = v;
            else       ((bf16*)dstv)[off] = __float2bfloat16(v);
        }
    }
}

// Partial row sums of exp(scores/8). (verified R9)
__global__ __launch_bounds__(256) void k_rowsum(
    const bf16* __restrict__ qh, const bf16* __restrict__ kh,
    float* __restrict__ rs)
{
    const int lane = threadIdx.x & 63;
    const int w    = threadIdx.x >> 6;
    const int lr   = lane & 15;
    const int lg   = lane >> 4;
    const int h    = blockIdx.y;
    const int part = blockIdx.z;
    const int qw   = blockIdx.x * 256 + w * 64;

    const bf16* qb = qh + (size_t)h * (S * DK);
    const bf16* kb = kh + (size_t)h * (S * DK);
    bf16x8 aq[4][2];
#pragma unroll
    for (int qs = 0; qs < 4; ++qs) {
        aq[qs][0] = load_frag(qb + (size_t)(qw + qs * 16 + lr) * DK + lg * 8);
        aq[qs][1] = load_frag(qb + (size_t)(qw + qs * 16 + lr) * DK + 32 + lg * 8);
    }

    float s[4] = {0.f, 0.f, 0.f, 0.f};
    for (int kp = part * RCHUNK; kp < part * RCHUNK + RCHUNK; kp += 16) {
        bf16x8 b0 = load_frag(kb + (size_t)(kp + lr) * DK + lg * 8);
        bf16x8 b1 = load_frag(kb + (size_t)(kp + lr) * DK + 32 + lg * 8);
#pragma unroll
        for (int qs = 0; qs < 4; ++qs) {
            f32x4 d = {};
            d = __builtin_amdgcn_mfma_f32_16x16x32_bf16(b0, aq[qs][0], d, 0, 0, 0);
            d = __builtin_amdgcn_mfma_f32_16x16x32_bf16(b1, aq[qs][1], d, 0, 0, 0);
            s[qs] += __expf(d[0] * 0.125f) + __expf(d[1] * 0.125f) +
                     __expf(d[2] * 0.125f) + __expf(d[3] * 0.125f);
        }
    }
#pragma unroll
    for (int qs = 0; qs < 4; ++qs) {
        float v = s[qs];
        v += __shfl_xor(v, 16, 64);
        v += __shfl_xor(v, 32, 64);
        if (lg == 0)
            rs[((size_t)part * NH + h) * S + qw + qs * 16 + lr] = v;
    }
}

// ---- k_attn helpers (A/B register staging) ----
__device__ inline void load_ktile(const bf16* kb, int kt, int lr, int lg,
                                  bf16x8 dst[4][2]) {
#pragma unroll
    for (int sub = 0; sub < 4; ++sub) {
        dst[sub][0] = load_frag(kb + (size_t)(kt + sub * 16 + lr) * DK + lg * 8);
        dst[sub][1] = load_frag(kb + (size_t)(kt + sub * 16 + lr) * DK + 32 + lg * 8);
    }
}
__device__ inline void load_vtile(const bf16* vb, int kt, int lr, int lg,
                                  bf16x8 dst[4][2]) {
#pragma unroll
    for (int dt = 0; dt < 4; ++dt) {
        dst[dt][0] = load_frag(vb + (size_t)(dt * 16 + lr) * S + kt + lg * 8);
        dst[dt][1] = load_frag(vb + (size_t)(dt * 16 + lr) * S + kt + 32 + lg * 8);
    }
}
__device__ inline void qk_tile(const bf16x8 kc[4][2], const bf16x8 aq[2][2],
                               const float linv[2], bf16 Pw[2][16][136],
                               int cb, int lr, int lg) {
#pragma unroll
    for (int sub = 0; sub < 4; ++sub) {
#pragma unroll
        for (int qs = 0; qs < 2; ++qs) {
            f32x4 d = {};
            d = __builtin_amdgcn_mfma_f32_16x16x32_bf16(kc[sub][0], aq[qs][0], d, 0, 0, 0);
            d = __builtin_amdgcn_mfma_f32_16x16x32_bf16(kc[sub][1], aq[qs][1], d, 0, 0, 0);
            bf16x4 pv;
            pv[0] = (__bf16)__expf(__builtin_fmaf(d[0], 0.125f, linv[qs]));
            pv[1] = (__bf16)__expf(__builtin_fmaf(d[1], 0.125f, linv[qs]));
            pv[2] = (__bf16)__expf(__builtin_fmaf(d[2], 0.125f, linv[qs]));
            pv[3] = (__bf16)__expf(__builtin_fmaf(d[3], 0.125f, linv[qs]));
            *reinterpret_cast<bf16x4*>(&Pw[qs][lr][cb + sub * 16 + 4 * lg]) = pv;
        }
    }
}
__device__ inline void pv_tile(const bf16x8 vc[4][2], const bf16 Pw[2][16][136],
                               f32x4 acc[2][4], int cb, int lr, int lg) {
    bf16x8 ap[2][2];
#pragma unroll
    for (int qs = 0; qs < 2; ++qs) {
        ap[qs][0] = *reinterpret_cast<const bf16x8*>(&Pw[qs][lr][cb + lg * 8]);
        ap[qs][1] = *reinterpret_cast<const bf16x8*>(&Pw[qs][lr][cb + 32 + lg * 8]);
    }
#pragma unroll
    for (int dt = 0; dt < 4; ++dt)
#pragma unroll
        for (int qs = 0; qs < 2; ++qs) {
            acc[qs][dt] = __builtin_amdgcn_mfma_f32_16x16x32_bf16(ap[qs][0], vc[dt][0], acc[qs][dt], 0, 0, 0);
            acc[qs][dt] = __builtin_amdgcn_mfma_f32_16x16x32_bf16(ap[qs][1], vc[dt][1], acc[qs][dt], 0, 0, 0);
        }
}

// k_attn with one-tile-ahead A/B register pipeline: all loads consumed by
// tile t+1 issue BEFORE pair-p's stores, so no vmcnt wait forces the
// nontemporal store queue to drain (stores complete in background).
__global__ __launch_bounds__(256, 2) void k_attn(
    const bf16* __restrict__ qh, const bf16* __restrict__ kh,
    const bf16* __restrict__ vt, const float* __restrict__ rs,
    void* __restrict__ doutv, bf16* __restrict__ ctxp,
    const int* __restrict__ flag)
{
    __shared__ __align__(16) bf16 Plds[4][2][16][136];
    const int isf32 = flag[0];
    const int lane = threadIdx.x & 63;
    const int w    = threadIdx.x >> 6;
    const int lr   = lane & 15, lg = lane >> 4;
    const int h    = blockIdx.y;
    const int half = blockIdx.z;
    const int q0w  = blockIdx.x * 128 + w * 32;   // wave's 32-q base
    const int k0   = half * KHALF;
    const int NT   = KHALF / 64;                  // 32 tiles

    const bf16* qb = qh + (size_t)h * (S * DK);
    const bf16* kb = kh + (size_t)h * (S * DK);
    const bf16* vb = vt + (size_t)h * (S * DK);

    bf16x8 aq[2][2];
    float  linv[2];
#pragma unroll
    for (int qs = 0; qs < 2; ++qs) {
        const int qr = q0w + qs * 16 + lr;
        aq[qs][0] = load_frag(qb + (size_t)qr * DK + lg * 8);
        aq[qs][1] = load_frag(qb + (size_t)qr * DK + 32 + lg * 8);
        float ssum = 0.f;
#pragma unroll
        for (int p = 0; p < RPARTS; ++p)
            ssum += rs[((size_t)p * NH + h) * S + qr];
        linv[qs] = -__logf(ssum);   // p = exp(s/8 + ln(1/sum))
    }

    float* poutF = (float*)doutv + (size_t)S * DM + (size_t)h * S * S;
    bf16*  poutB = (bf16*)doutv  + (size_t)S * DM + (size_t)h * S * S;
    const int fr2 = lane >> 5;          // 0..1
    const int fc2 = (lane & 31) * 4;    // 0..124

    bf16x8 kA[4][2], vA[4][2], kB[4][2], vB[4][2];
    load_ktile(kb, k0, lr, lg, kA);
    load_vtile(vb, k0, lr, lg, vA);

    f32x4 acc[2][4] = {};
    for (int p = 0; p < NT / 2; ++p) {
        const int ktA  = k0 + 2 * p * 64;
        const int ktB  = ktA + 64;
        const int ktA2 = (2 * p + 2 < NT) ? ktB + 64 : ktB;   // clamped prefetch
        // tile A: prefetch B, compute A
        load_ktile(kb, ktB, lr, lg, kB);
        load_vtile(vb, ktB, lr, lg, vB);
        qk_tile(kA, aq, linv, Plds[w], 0, lr, lg);
        pv_tile(vA, Plds[w], acc, 0, lr, lg);
        // tile B: prefetch next-A, compute B
        load_ktile(kb, ktA2, lr, lg, kA);
        load_vtile(vb, ktA2, lr, lg, vA);
        qk_tile(kB, aq, linv, Plds[w], 64, lr, lg);
        pv_tile(vB, Plds[w], acc, 64, lr, lg);
        // flush pair (stores AFTER next tiles' loads were issued)
        if (isf32) {
#pragma unroll
            for (int j = 0; j < 16; ++j) {
                const int row = 2 * j + fr2;           // 0..31
                const int qs = row >> 4, rr = row & 15;
                bf16x4 x = *reinterpret_cast<const bf16x4*>(&Plds[w][qs][rr][fc2]);
                f32x4 o;
                o[0] = (float)x[0]; o[1] = (float)x[1];
                o[2] = (float)x[2]; o[3] = (float)x[3];
                __builtin_nontemporal_store(
                    o, reinterpret_cast<f32x4*>(
                           poutF + (size_t)(q0w + row) * S + ktA + fc2));
            }
        } else {
#pragma unroll
            for (int j = 0; j < 16; ++j) {
                const int row = 2 * j + fr2;
                const int qs = row >> 4, rr = row & 15;
                bf16x4 x = *reinterpret_cast<const bf16x4*>(&Plds[w][qs][rr][fc2]);
                *reinterpret_cast<bf16x4*>(
                    poutB + (size_t)(q0w + row) * S + ktA + fc2) = x;
            }
        }
    }
    bf16* cp = ctxp + (size_t)half * S * DM;
#pragma unroll
    for (int qs = 0; qs < 2; ++qs)
#pragma unroll
        for (int dt = 0; dt < 4; ++dt)
#pragma unroll
            for (int r = 0; r < 4; ++r)
                cp[(size_t)(q0w + qs * 16 + 4 * lg + r) * DM + h * DK + dt * 16 + lr] =
                    __float2bfloat16(acc[qs][dt][r]);
}

extern "C" void kernel_launch(void* const* d_in, const int* in_sizes, int n_in,
                              void* d_out, int out_size, void* d_ws, size_t ws_size,
                              hipStream_t stream) {
    char* wsb = (char*)d_ws;
    int*   flag = (int*)wsb;                                    // 16 B
    float* rs   = (float*)(wsb + 16);                           // RPARTS*NH*S f32
    bf16*  conv = (bf16*)(wsb + 16 + (size_t)RPARTS * NH * S * 4);

    const size_t nQ = (size_t)S * DM, nW = (size_t)DM * DM, nB = DM;
    bf16* Qc  = conv;
    bf16* Kc  = Qc + nQ;
    bf16* Vc  = Kc + nQ;
    bf16* Wqc = Vc + nQ;
    bf16* Wkc = Wqc + nW;
    bf16* Wvc = Wkc + nW;
    bf16* Woc = Wvc + nW;
    bf16* bqc = Woc + nW;
    bf16* bkc = bqc + nB;
    bf16* bvc = bkc + nB;
    bf16* boc = bvc + nB;
    bf16* qh  = boc + nB;
    bf16* kh  = qh + nQ;
    bf16* vt  = kh + nQ;
    // alias (Qc/Kc dead after projections): ctxp = 2*nQ bf16 partial ctx
    bf16* ctxp = Qc;

    const size_t need = (size_t)((char*)(vt + nQ) - wsb);
    if (ws_size < need) return;

    dim3 blk(256);
    k_detect<<<1, 64, 0, stream>>>((const unsigned int*)d_in[0], flag);

    k_cast3<<<dim3((int)(nQ / 2048), 3), blk, 0, stream>>>(
        d_in[0], d_in[1], d_in[2], Qc, Kc, Vc, (int)nQ, flag);
    k_cast4<<<dim3((int)(nW / 2048), 4), blk, 0, stream>>>(
        d_in[3], d_in[5], d_in[7], d_in[9], Wqc, Wkc, Wvc, Woc, (int)nW, flag);
    k_cast4<<<dim3(1, 4), blk, 0, stream>>>(
        d_in[4], d_in[6], d_in[8], d_in[10], bqc, bkc, bvc, boc, (int)nB, flag);

    k_proj_qkv<<<dim3(S / 64, DM / 64, 3), blk, 0, stream>>>(
        Qc, Kc, Vc, Wqc, Wkc, Wvc, bqc, bkc, bvc, qh, kh, vt, flag);
    k_rowsum<<<dim3(S / 256, NH, RPARTS), blk, 0, stream>>>(qh, kh, rs);
    k_attn<<<dim3(S / 128, NH, KSPLIT), blk, 0, stream>>>(qh, kh, vt, rs, d_out, ctxp, flag);
    k_proj_out<<<dim3(S / 64, DM / 64), blk, 0, stream>>>(ctxp, Woc, boc, d_out, flag);
}

// Round 13
// 464.666 us; speedup vs baseline: 1.0643x; 1.0082x over previous
//
#include <hip/hip_runtime.h>
#include <hip/hip_bf16.h>

#define S 4096
#define DM 768
#define NH 12
#define DK 64
#define RPARTS 8
#define RCHUNK (S / RPARTS)

typedef __bf16 bf16x8 __attribute__((ext_vector_type(8)));
typedef __bf16 bf16x4 __attribute__((ext_vector_type(4)));
typedef float f32x4 __attribute__((ext_vector_type(4)));
using bf16 = __hip_bfloat16;

__device__ inline bf16x8 load_frag(const bf16* p) {
    return *reinterpret_cast<const bf16x8*>(p);
}

// Detect input dtype (f32 vs bf16) from bit patterns; flag=1 -> f32.
__global__ void k_detect(const unsigned int* __restrict__ q, int* __restrict__ flag) {
    const int lane = threadIdx.x;  // 64 threads
    int cnt = 0;
    for (int i = lane; i < 1024; i += 64) {
        const unsigned int w = q[i];
        const int e = (w >> 7) & 0xFF;
        if (e >= 192 || (e > 0 && e < 64)) cnt++;
    }
    for (int m = 1; m < 64; m <<= 1) cnt += __shfl_xor(cnt, m, 64);
    if (lane == 0) flag[0] = (cnt > 64) ? 1 : 0;
}

struct CastArgs {
    const void* s[11];
    bf16* d[11];
    int n[11];
};

__global__ __launch_bounds__(256) void k_cast_all(CastArgs a, const int* __restrict__ flag) {
    const int t = blockIdx.y;
    const void* src = a.s[t];
    bf16* dst = a.d[t];
    const int n = a.n[t];
    const int isf32 = flag[0];
    const int stride = gridDim.x * 256 * 8;
    for (int i = (blockIdx.x * 256 + threadIdx.x) * 8; i < n; i += stride) {
        if (isf32) {
            const float* s = (const float*)src + i;
            float4 x = *(const float4*)(s);
            float4 y = *(const float4*)(s + 4);
            bf16x8 o;
            o[0] = (__bf16)x.x; o[1] = (__bf16)x.y; o[2] = (__bf16)x.z; o[3] = (__bf16)x.w;
            o[4] = (__bf16)y.x; o[5] = (__bf16)y.y; o[6] = (__bf16)y.z; o[7] = (__bf16)y.w;
            *reinterpret_cast<bf16x8*>(dst + i) = o;
        } else {
            *reinterpret_cast<bf16x8*>(dst + i) =
                *reinterpret_cast<const bf16x8*>((const __bf16*)src + i);
        }
    }
}

// x @ W^T + b core. mode 0/1: head-split [H][S][DK]; mode 2: transposed [DM][S].
__device__ inline void proj_body(
    const bf16* __restrict__ X, const bf16* __restrict__ W,
    const bf16* __restrict__ bias, void* __restrict__ dstv, int mode, int isf32)
{
    const int lane = threadIdx.x & 63;
    const int w    = threadIdx.x >> 6;
    const int lr   = lane & 15, lg = lane >> 4;
    const int rbase = blockIdx.x * 64 + w * 16;
    const int nbase = blockIdx.y * 64;

    f32x4 acc[4] = {};
    const bf16* xrow = X + (size_t)(rbase + lr) * DM + lg * 8;
    for (int kk = 0; kk < DM; kk += 32) {
        bf16x8 a = load_frag(xrow + kk);
#pragma unroll
        for (int nt = 0; nt < 4; ++nt) {
            bf16x8 b = load_frag(W + (size_t)(nbase + nt * 16 + lr) * DM + kk + lg * 8);
            acc[nt] = __builtin_amdgcn_mfma_f32_16x16x32_bf16(a, b, acc[nt], 0, 0, 0);
        }
    }
#pragma unroll
    for (int nt = 0; nt < 4; ++nt) {
        const int col = nbase + nt * 16 + lr;
        const float bv = __bfloat162float(bias[col]);
#pragma unroll
        for (int r = 0; r < 4; ++r) {
            const int row = rbase + lg * 4 + r;
            const float v = acc[nt][r] + bv;
            size_t off;
            if (mode == 2) off = (size_t)col * S + row;
            else           off = (size_t)(col >> 6) * (S * DK) + (size_t)row * DK + (col & 63);
            ((bf16*)dstv)[off] = __float2bfloat16(v);
        }
    }
}

// Fused Q/K/V projections: blockIdx.z selects tensor (0->qh, 1->kh, 2->vt).
__global__ __launch_bounds__(256) void k_proj_qkv(
    const bf16* __restrict__ Qc, const bf16* __restrict__ Kc, const bf16* __restrict__ Vc,
    const bf16* __restrict__ Wq, const bf16* __restrict__ Wk, const bf16* __restrict__ Wv,
    const bf16* __restrict__ bq, const bf16* __restrict__ bk, const bf16* __restrict__ bv,
    bf16* __restrict__ qh, bf16* __restrict__ kh, bf16* __restrict__ vt,
    const int* __restrict__ flag)
{
    const int z = blockIdx.z;
    const bf16* X = (z == 0) ? Qc : (z == 1) ? Kc : Vc;
    const bf16* W = (z == 0) ? Wq : (z == 1) ? Wk : Wv;
    const bf16* B = (z == 0) ? bq : (z == 1) ? bk : bv;
    bf16* D      = (z == 0) ? qh : (z == 1) ? kh : vt;
    proj_body(X, W, B, D, (z == 2) ? 2 : 0, flag[0]);
}

// Output projection: out = ctx @ Wo^T + bo, dtype per flag.
__global__ __launch_bounds__(256) void k_proj_out(
    const bf16* __restrict__ ctx, const bf16* __restrict__ W,
    const bf16* __restrict__ bias, void* __restrict__ dstv,
    const int* __restrict__ flag)
{
    const int isf32 = flag[0];
    const int lane = threadIdx.x & 63;
    const int w    = threadIdx.x >> 6;
    const int lr   = lane & 15, lg = lane >> 4;
    const int rbase = blockIdx.x * 64 + w * 16;
    const int nbase = blockIdx.y * 64;

    f32x4 acc[4] = {};
    const bf16* xrow = ctx + (size_t)(rbase + lr) * DM + lg * 8;
    for (int kk = 0; kk < DM; kk += 32) {
        bf16x8 a = load_frag(xrow + kk);
#pragma unroll
        for (int nt = 0; nt < 4; ++nt) {
            bf16x8 b = load_frag(W + (size_t)(nbase + nt * 16 + lr) * DM + kk + lg * 8);
            acc[nt] = __builtin_amdgcn_mfma_f32_16x16x32_bf16(a, b, acc[nt], 0, 0, 0);
        }
    }
#pragma unroll
    for (int nt = 0; nt < 4; ++nt) {
        const int col = nbase + nt * 16 + lr;
        const float bv = __bfloat162float(bias[col]);
#pragma unroll
        for (int r = 0; r < 4; ++r) {
            const int row = rbase + lg * 4 + r;
            const float v = acc[nt][r] + bv;
            const size_t off = (size_t)row * DM + col;
            if (isf32) ((float*)dstv)[off] = v;
            else       ((bf16*)dstv)[off] = __float2bfloat16(v);
        }
    }
}

// Partial row sums of exp(scores/8). (verified R9)
__global__ __launch_bounds__(256) void k_rowsum(
    const bf16* __restrict__ qh, const bf16* __restrict__ kh,
    float* __restrict__ rs)
{
    const int lane = threadIdx.x & 63;
    const int w    = threadIdx.x >> 6;
    const int lr   = lane & 15;
    const int lg   = lane >> 4;
    const int h    = blockIdx.y;
    const int part = blockIdx.z;
    const int qw   = blockIdx.x * 256 + w * 64;

    const bf16* qb = qh + (size_t)h * (S * DK);
    const bf16* kb = kh + (size_t)h * (S * DK);
    bf16x8 aq[4][2];
#pragma unroll
    for (int qs = 0; qs < 4; ++qs) {
        aq[qs][0] = load_frag(qb + (size_t)(qw + qs * 16 + lr) * DK + lg * 8);
        aq[qs][1] = load_frag(qb + (size_t)(qw + qs * 16 + lr) * DK + 32 + lg * 8);
    }

    float s[4] = {0.f, 0.f, 0.f, 0.f};
    for (int kp = part * RCHUNK; kp < part * RCHUNK + RCHUNK; kp += 16) {
        bf16x8 b0 = load_frag(kb + (size_t)(kp + lr) * DK + lg * 8);
        bf16x8 b1 = load_frag(kb + (size_t)(kp + lr) * DK + 32 + lg * 8);
#pragma unroll
        for (int qs = 0; qs < 4; ++qs) {
            f32x4 d = {};
            d = __builtin_amdgcn_mfma_f32_16x16x32_bf16(b0, aq[qs][0], d, 0, 0, 0);
            d = __builtin_amdgcn_mfma_f32_16x16x32_bf16(b1, aq[qs][1], d, 0, 0, 0);
            s[qs] += __expf(d[0] * 0.125f) + __expf(d[1] * 0.125f) +
                     __expf(d[2] * 0.125f) + __expf(d[3] * 0.125f);
        }
    }
#pragma unroll
    for (int qs = 0; qs < 4; ++qs) {
        float v = s[qs];
        v += __shfl_xor(v, 16, 64);
        v += __shfl_xor(v, 32, 64);
        if (lg == 0)
            rs[((size_t)part * NH + h) * S + qw + qs * 16 + lr] = v;
    }
}

// R11-verified body, extended: 2-wave blocks (32 q-rows/wave), KSPLIT=1,
// 4-tile (256-col) staging so the flush writes ONE FULL 1KB row-segment per
// store instruction. V-prefetch per tile; no barrier (Plds wave-private);
// ctx written directly (single k-range per q).
__global__ __launch_bounds__(128) void k_attn(
    const bf16* __restrict__ qh, const bf16* __restrict__ kh,
    const bf16* __restrict__ vt, const float* __restrict__ rs,
    void* __restrict__ doutv, bf16* __restrict__ ctx,
    const int* __restrict__ flag)
{
    __shared__ __align__(16) bf16 Plds[2][2][16][264];
    const int isf32 = flag[0];
    const int lane = threadIdx.x & 63;
    const int w    = threadIdx.x >> 6;           // 0..1
    const int lr   = lane & 15, lg = lane >> 4;
    const int h    = blockIdx.y;
    const int q0w  = blockIdx.x * 64 + w * 32;   // wave's 32-q base

    const bf16* qb = qh + (size_t)h * (S * DK);
    const bf16* kb = kh + (size_t)h * (S * DK);
    const bf16* vb = vt + (size_t)h * (S * DK);

    bf16x8 aq[2][2];
    float  linv[2];
#pragma unroll
    for (int qs = 0; qs < 2; ++qs) {
        const int qr = q0w + qs * 16 + lr;
        aq[qs][0] = load_frag(qb + (size_t)qr * DK + lg * 8);
        aq[qs][1] = load_frag(qb + (size_t)qr * DK + 32 + lg * 8);
        float ssum = 0.f;
#pragma unroll
        for (int p = 0; p < RPARTS; ++p)
            ssum += rs[((size_t)p * NH + h) * S + qr];
        linv[qs] = -__logf(ssum);   // p = exp(s/8 + ln(1/sum))
    }

    float* poutF = (float*)doutv + (size_t)S * DM + (size_t)h * S * S;
    bf16*  poutB = (bf16*)doutv  + (size_t)S * DM + (size_t)h * S * S;

    f32x4 acc[2][4] = {};
    for (int g = 0; g < S / 256; ++g) {          // 16 groups of 4 tiles
#pragma unroll
        for (int tt = 0; tt < 4; ++tt) {
            const int kt = g * 256 + tt * 64;
            const int cb = tt * 64;              // column base in Plds
            // ---- V prefetch for this tile (independent of P) ----
            bf16x8 vv[4][2];
#pragma unroll
            for (int dt = 0; dt < 4; ++dt) {
                vv[dt][0] = load_frag(vb + (size_t)(dt * 16 + lr) * S + kt + lg * 8);
                vv[dt][1] = load_frag(vb + (size_t)(dt * 16 + lr) * S + kt + 32 + lg * 8);
            }
            // ---- QK^T (swapped: D rows = k, cols = q), exp, stage bf16 ----
#pragma unroll
            for (int sub = 0; sub < 4; ++sub) {
                const int kp = kt + sub * 16;
                bf16x8 b0 = load_frag(kb + (size_t)(kp + lr) * DK + lg * 8);
                bf16x8 b1 = load_frag(kb + (size_t)(kp + lr) * DK + 32 + lg * 8);
#pragma unroll
                for (int qs = 0; qs < 2; ++qs) {
                    f32x4 d = {};
                    d = __builtin_amdgcn_mfma_f32_16x16x32_bf16(b0, aq[qs][0], d, 0, 0, 0);
                    d = __builtin_amdgcn_mfma_f32_16x16x32_bf16(b1, aq[qs][1], d, 0, 0, 0);
                    bf16x4 pv;
                    pv[0] = (__bf16)__expf(__builtin_fmaf(d[0], 0.125f, linv[qs]));
                    pv[1] = (__bf16)__expf(__builtin_fmaf(d[1], 0.125f, linv[qs]));
                    pv[2] = (__bf16)__expf(__builtin_fmaf(d[2], 0.125f, linv[qs]));
                    pv[3] = (__bf16)__expf(__builtin_fmaf(d[3], 0.125f, linv[qs]));
                    *reinterpret_cast<bf16x4*>(
                        &Plds[w][qs][lr][cb + sub * 16 + 4 * lg]) = pv;
                }
            }
            // ---- PV on this 64-k tile (prefetched V, shared across qs) ----
            bf16x8 ap[2][2];
#pragma unroll
            for (int qs = 0; qs < 2; ++qs) {
                ap[qs][0] = *reinterpret_cast<const bf16x8*>(&Plds[w][qs][lr][cb + lg * 8]);
                ap[qs][1] = *reinterpret_cast<const bf16x8*>(&Plds[w][qs][lr][cb + 32 + lg * 8]);
            }
#pragma unroll
            for (int dt = 0; dt < 4; ++dt) {
#pragma unroll
                for (int qs = 0; qs < 2; ++qs) {
                    acc[qs][dt] = __builtin_amdgcn_mfma_f32_16x16x32_bf16(ap[qs][0], vv[dt][0], acc[qs][dt], 0, 0, 0);
                    acc[qs][dt] = __builtin_amdgcn_mfma_f32_16x16x32_bf16(ap[qs][1], vv[dt][1], acc[qs][dt], 0, 0, 0);
                }
            }
        }
        // ---- flush 4 tiles: 32 rows x 256 cols; ONE full row per store ----
        const int ktbase = g * 256;
        if (isf32) {
#pragma unroll
            for (int j = 0; j < 32; ++j) {
                const int qs = j >> 4, rr = j & 15;
                bf16x4 x = *reinterpret_cast<const bf16x4*>(&Plds[w][qs][rr][lane * 4]);
                f32x4 o;
                o[0] = (float)x[0]; o[1] = (float)x[1];
                o[2] = (float)x[2]; o[3] = (float)x[3];
                __builtin_nontemporal_store(
                    o, reinterpret_cast<f32x4*>(
                           poutF + (size_t)(q0w + j) * S + ktbase + lane * 4));
            }
        } else {
#pragma unroll
            for (int j = 0; j < 32; ++j) {
                const int qs = j >> 4, rr = j & 15;
                bf16x4 x = *reinterpret_cast<const bf16x4*>(&Plds[w][qs][rr][lane * 4]);
                *reinterpret_cast<bf16x4*>(
                    poutB + (size_t)(q0w + j) * S + ktbase + lane * 4) = x;
            }
        }
    }
    // epilogue: ctx[q][h*64+d] (bf16), single k-range per q -> direct write
#pragma unroll
    for (int qs = 0; qs < 2; ++qs)
#pragma unroll
        for (int dt = 0; dt < 4; ++dt)
#pragma unroll
            for (int r = 0; r < 4; ++r)
                ctx[(size_t)(q0w + qs * 16 + 4 * lg + r) * DM + h * DK + dt * 16 + lr] =
                    __float2bfloat16(acc[qs][dt][r]);
}

extern "C" void kernel_launch(void* const* d_in, const int* in_sizes, int n_in,
                              void* d_out, int out_size, void* d_ws, size_t ws_size,
                              hipStream_t stream) {
    char* wsb = (char*)d_ws;
    int*   flag = (int*)wsb;                                    // 16 B
    float* rs   = (float*)(wsb + 16);                           // RPARTS*NH*S f32
    bf16*  conv = (bf16*)(wsb + 16 + (size_t)RPARTS * NH * S * 4);

    const size_t nQ = (size_t)S * DM, nW = (size_t)DM * DM, nB = DM;
    bf16* Qc  = conv;
    bf16* Kc  = Qc + nQ;
    bf16* Vc  = Kc + nQ;
    bf16* Wqc = Vc + nQ;
    bf16* Wkc = Wqc + nW;
    bf16* Wvc = Wkc + nW;
    bf16* Woc = Wvc + nW;
    bf16* bqc = Woc + nW;
    bf16* bkc = bqc + nB;
    bf16* bvc = bkc + nB;
    bf16* boc = bvc + nB;
    bf16* qh  = boc + nB;
    bf16* kh  = qh + nQ;
    bf16* vt  = kh + nQ;
    // alias (Qc dead after projections): ctx = nQ bf16
    bf16* ctx = Qc;

    const size_t need = (size_t)((char*)(vt + nQ) - wsb);
    if (ws_size < need) return;

    dim3 blk(256);
    k_detect<<<1, 64, 0, stream>>>((const unsigned int*)d_in[0], flag);

    CastArgs ca;
    ca.s[0] = d_in[0];  ca.d[0] = Qc;   ca.n[0] = (int)nQ;
    ca.s[1] = d_in[1];  ca.d[1] = Kc;   ca.n[1] = (int)nQ;
    ca.s[2] = d_in[2];  ca.d[2] = Vc;   ca.n[2] = (int)nQ;
    ca.s[3] = d_in[3];  ca.d[3] = Wqc;  ca.n[3] = (int)nW;
    ca.s[4] = d_in[5];  ca.d[4] = Wkc;  ca.n[4] = (int)nW;
    ca.s[5] = d_in[7];  ca.d[5] = Wvc;  ca.n[5] = (int)nW;
    ca.s[6] = d_in[9];  ca.d[6] = Woc;  ca.n[6] = (int)nW;
    ca.s[7] = d_in[4];  ca.d[7] = bqc;  ca.n[7] = (int)nB;
    ca.s[8] = d_in[6];  ca.d[8] = bkc;  ca.n[8] = (int)nB;
    ca.s[9] = d_in[8];  ca.d[9] = bvc;  ca.n[9] = (int)nB;
    ca.s[10] = d_in[10]; ca.d[10] = boc; ca.n[10] = (int)nB;
    k_cast_all<<<dim3(512, 11), blk, 0, stream>>>(ca, flag);

    k_proj_qkv<<<dim3(S / 64, DM / 64, 3), blk, 0, stream>>>(
        Qc, Kc, Vc, Wqc, Wkc, Wvc, bqc, bkc, bvc, qh, kh, vt, flag);
    k_rowsum<<<dim3(S / 256, NH, RPARTS), blk, 0, stream>>>(qh, kh, rs);
    k_attn<<<dim3(S / 64, NH), dim3(128), 0, stream>>>(qh, kh, vt, rs, d_out, ctx, flag);
    k_proj_out<<<dim3(S / 64, DM / 64), blk, 0, stream>>>(ctx, Woc, boc, d_out, flag);
}